// Round 1
// baseline (233.774 us; speedup 1.0000x reference)
//
#include <hip/hip_runtime.h>
#include <stdint.h>

typedef unsigned short ushort_t;
typedef __attribute__((ext_vector_type(8))) short short8;
typedef __attribute__((ext_vector_type(4))) float f32x4;

// ws layout (bf16 elements)
#define OFF_QIN  0u
#define OFF_KIN  4194304u
#define OFF_VIN  8388608u
#define OFF_WQ   12582912u
#define OFF_WK   13631488u
#define OFF_WV   14680064u
#define OFF_QP   15728640u   // Q projected (scaled by 0.125*log2e), [4096][1024]
#define OFF_KP   19922944u   // K projected, [4096][1024]
#define OFF_VT   24117248u   // V projected TRANSPOSED: [(g*64+d)*1024 + m]

__device__ __forceinline__ ushort_t f2bf(float f) {
  union { float f; unsigned u; } x; x.f = f;
  unsigned r = (x.u + 0x7fffu + ((x.u >> 16) & 1u)) >> 16;
  return (ushort_t)r;
}

__device__ __forceinline__ void gl_lds16(const void* g, void* l) {
  __builtin_amdgcn_global_load_lds(
      (const __attribute__((address_space(1))) void*)g,
      (__attribute__((address_space(3))) void*)l, 16, 0, 0);
}

// ---------------- convert fp32 -> bf16 (all six inputs) ----------------
__global__ void cvt_kernel(const float* __restrict__ q, const float* __restrict__ k,
                           const float* __restrict__ v, const float* __restrict__ wq,
                           const float* __restrict__ wk, const float* __restrict__ wv,
                           ushort_t* __restrict__ ws) {
  int cid = blockIdx.x * 256 + threadIdx.x;  // 1,966,080 chunks of 8 elems
  const float* src; int loc;
  if (cid < 1572864) {            // q,k,v: 524288 chunks each
    int seg = cid >> 19; loc = cid & 524287;
    src = (seg == 0) ? q : (seg == 1) ? k : v;
  } else {                        // weights: 131072 chunks each
    int c2 = cid - 1572864; int seg = c2 >> 17; loc = c2 & 131071;
    src = (seg == 0) ? wq : (seg == 1) ? wk : wv;
  }
  const float4* s4 = (const float4*)(src + (size_t)loc * 8);
  float4 a = s4[0], b = s4[1];
  short8 r;
  r[0] = f2bf(a.x); r[1] = f2bf(a.y); r[2] = f2bf(a.z); r[3] = f2bf(a.w);
  r[4] = f2bf(b.x); r[5] = f2bf(b.y); r[6] = f2bf(b.z); r[7] = f2bf(b.w);
  *(short8*)(ws + (size_t)cid * 8) = r;
}

// ---------------- fused Q/K/V projection GEMM: C = A * W^T ----------------
// z=0: Q (epilogue scale 0.125*log2e), z=1: K, z=2: V stored transposed (vt)
__global__ __launch_bounds__(256) void gemm_qkv(ushort_t* __restrict__ ws) {
  int z = blockIdx.z;
  const ushort_t* A = ws + (z == 0 ? OFF_QIN : z == 1 ? OFF_KIN : OFF_VIN);
  const ushort_t* W = ws + (z == 0 ? OFF_WQ  : z == 1 ? OFF_WK  : OFF_WV);
  ushort_t* C       = ws + (z == 0 ? OFF_QP  : z == 1 ? OFF_KP  : OFF_VT);
  float scale = (z == 0) ? 0.18033688011112042f : 1.0f;  // (1/8)*log2(e)

  __shared__ ushort_t As[128 * 32];
  __shared__ ushort_t Bs[128 * 32];

  int tid = threadIdx.x, lane = tid & 63, wv = tid >> 6;
  int wr = wv >> 1, wc = wv & 1;
  int r16 = lane & 15, kg = lane >> 4;
  int srow = lane >> 2;            // staging row-within-chunk
  int scol = (lane & 3) * 8;       // staging col

  int rowA0 = blockIdx.x * 128;
  int colB0 = blockIdx.y * 128;

  f32x4 acc[4][4];
#pragma unroll
  for (int m = 0; m < 4; m++)
#pragma unroll
    for (int n = 0; n < 4; n++) acc[m][n] = (f32x4){0.f, 0.f, 0.f, 0.f};

  for (int k0 = 0; k0 < 1024; k0 += 32) {
    __syncthreads();
#pragma unroll
    for (int r = 0; r < 2; r++) {
      int ch = wv * 2 + r;
      int row = ch * 16 + srow;
      gl_lds16(A + (size_t)(rowA0 + row) * 1024 + k0 + scol, &As[ch * 512]);
      gl_lds16(W + (size_t)(colB0 + row) * 1024 + k0 + scol, &Bs[ch * 512]);
    }
    __syncthreads();
    short8 af[4], bfr[4];
#pragma unroll
    for (int m = 0; m < 4; m++)
      af[m] = *(const short8*)&As[(wr * 64 + m * 16 + r16) * 32 + kg * 8];
#pragma unroll
    for (int n = 0; n < 4; n++)
      bfr[n] = *(const short8*)&Bs[(wc * 64 + n * 16 + r16) * 32 + kg * 8];
#pragma unroll
    for (int m = 0; m < 4; m++)
#pragma unroll
      for (int n = 0; n < 4; n++)
        acc[m][n] = __builtin_amdgcn_mfma_f32_16x16x32_bf16(af[m], bfr[n], acc[m][n], 0, 0, 0);
  }

  if (z < 2) {
#pragma unroll
    for (int m = 0; m < 4; m++)
#pragma unroll
      for (int n = 0; n < 4; n++) {
        int col = colB0 + wc * 64 + n * 16 + r16;
#pragma unroll
        for (int r = 0; r < 4; r++) {
          int row = rowA0 + wr * 64 + m * 16 + kg * 4 + r;
          C[(size_t)row * 1024 + col] = f2bf(acc[m][n][r] * scale);
        }
      }
  } else {
    // vt[(g*64+d)*1024 + mseq]; g=b*16+(n>>6), mseq=(n&63)*16+h, h=e>>6, d=e&63
#pragma unroll
    for (int m = 0; m < 4; m++)
#pragma unroll
      for (int n = 0; n < 4; n++) {
        int col = colB0 + wc * 64 + n * 16 + r16;
        int h = col >> 6, d = col & 63;
#pragma unroll
        for (int r = 0; r < 4; r++) {
          int row = rowA0 + wr * 64 + m * 16 + kg * 4 + r;
          int b = row >> 10, nin = row & 1023;
          int g = b * 16 + (nin >> 6);
          int mseq = (nin & 63) * 16 + h;
          C[((size_t)g * 64 + d) * 1024 + mseq] = f2bf(acc[m][n][r]);
        }
      }
  }
}

// ---------------- flash attention over 64 groups, N=1024, D=64 ----------------
__global__ __launch_bounds__(256) void attn_kernel(const ushort_t* __restrict__ ws,
                                                   float* __restrict__ out) {
  const ushort_t* Qp = ws + OFF_QP;
  const ushort_t* Kp = ws + OFF_KP;
  const ushort_t* Vt = ws + OFF_VT;

  __shared__ ushort_t Ks[64 * 72];      // K tile [m'][d], +8 pad (kills bank conflicts)
  __shared__ ushort_t Vs[64 * 72];      // V tile [d][m'], +8 pad
  __shared__ ushort_t Ps[4][16 * 72];   // per-wave P tile [qrow][m'], +8 pad

  int g = blockIdx.x;   // group = (b, 64-token chunk)
  int qt = blockIdx.y;  // q-tile of 64 m-rows
  int b = g >> 4, cc = g & 15;
  int tid = threadIdx.x, lane = tid & 63, wv = tid >> 6;
  int r16 = lane & 15, kg = lane >> 4;

  // Q fragments for this wave's 16 m-rows: m = qt*64 + wv*16 + r16
  // -> n = cc*64 + qt*4 + wv (same for whole wave), e = r16*64 + d
  short8 aq[2];
  {
    size_t base = ((size_t)(b * 1024 + cc * 64 + qt * 4 + wv)) * 1024 + r16 * 64;
    aq[0] = *(const short8*)&Qp[base + kg * 8];
    aq[1] = *(const short8*)&Qp[base + 32 + kg * 8];
  }

  f32x4 O[4];
#pragma unroll
  for (int i = 0; i < 4; i++) O[i] = (f32x4){0.f, 0.f, 0.f, 0.f};
  float mo[4] = {-1e30f, -1e30f, -1e30f, -1e30f};
  float lo[4] = {0.f, 0.f, 0.f, 0.f};

  int srr = tid >> 2;          // row (K) / d (V) this thread stages
  int sc0 = (tid & 3) * 16;    // col start (32B per thread)
  const int nbase = b * 1024 + cc * 64;

  for (int it = 0; it < 16; it++) {
    __syncthreads();
    {
      // stage K: Ks[rr][d]; global row m'=it*64+rr -> n=nbase+it*4+(rr>>4), e=(rr&15)*64+d
      size_t src = ((size_t)(nbase + it * 4 + (srr >> 4))) * 1024 + (srr & 15) * 64 + sc0;
      short8 v0 = *(const short8*)&Kp[src];
      short8 v1 = *(const short8*)&Kp[src + 8];
      *(short8*)&Ks[srr * 72 + sc0] = v0;
      *(short8*)&Ks[srr * 72 + sc0 + 8] = v1;
      // stage V: Vs[d][m'] from vt (already transposed globally)
      size_t sv = ((size_t)g * 64 + srr) * 1024 + it * 64 + sc0;
      short8 w0 = *(const short8*)&Vt[sv];
      short8 w1 = *(const short8*)&Vt[sv + 8];
      *(short8*)&Vs[srr * 72 + sc0] = w0;
      *(short8*)&Vs[srr * 72 + sc0 + 8] = w1;
    }
    __syncthreads();

    // S = Q K^T (Q pre-scaled so exp2 gives softmax)
    f32x4 s[4];
#pragma unroll
    for (int jc = 0; jc < 4; jc++) {
      s[jc] = (f32x4){0.f, 0.f, 0.f, 0.f};
#pragma unroll
      for (int c2 = 0; c2 < 2; c2++) {
        short8 bk = *(const short8*)&Ks[(jc * 16 + r16) * 72 + c2 * 32 + kg * 8];
        s[jc] = __builtin_amdgcn_mfma_f32_16x16x32_bf16(aq[c2], bk, s[jc], 0, 0, 0);
      }
    }
    // online softmax; C-layout: row = kg*4+r, col = jc*16+r16
    float mn[4], al[4], ls[4];
#pragma unroll
    for (int r = 0; r < 4; r++) {
      float mx = fmaxf(fmaxf(s[0][r], s[1][r]), fmaxf(s[2][r], s[3][r]));
#pragma unroll
      for (int off = 1; off < 16; off <<= 1) mx = fmaxf(mx, __shfl_xor(mx, off, 64));
      mn[r] = fmaxf(mo[r], mx);
      al[r] = exp2f(mo[r] - mn[r]);
      ls[r] = 0.f;
    }
#pragma unroll
    for (int jc = 0; jc < 4; jc++)
#pragma unroll
      for (int r = 0; r < 4; r++) {
        float p = exp2f(s[jc][r] - mn[r]);
        s[jc][r] = p;
        ls[r] += p;
      }
#pragma unroll
    for (int r = 0; r < 4; r++) {
#pragma unroll
      for (int off = 1; off < 16; off <<= 1) ls[r] += __shfl_xor(ls[r], off, 64);
      lo[r] = lo[r] * al[r] + ls[r];
      mo[r] = mn[r];
    }
#pragma unroll
    for (int dc = 0; dc < 4; dc++) {
      O[dc][0] *= al[0]; O[dc][1] *= al[1]; O[dc][2] *= al[2]; O[dc][3] *= al[3];
    }
    // P -> LDS (bf16), wave-private buffer (no barrier needed)
#pragma unroll
    for (int jc = 0; jc < 4; jc++)
#pragma unroll
      for (int r = 0; r < 4; r++)
        Ps[wv][(kg * 4 + r) * 72 + jc * 16 + r16] = f2bf(s[jc][r]);
    // O += P V
    short8 pa0 = *(const short8*)&Ps[wv][r16 * 72 + kg * 8];
    short8 pa1 = *(const short8*)&Ps[wv][r16 * 72 + 32 + kg * 8];
#pragma unroll
    for (int dc = 0; dc < 4; dc++) {
      short8 bv0 = *(const short8*)&Vs[(dc * 16 + r16) * 72 + kg * 8];
      O[dc] = __builtin_amdgcn_mfma_f32_16x16x32_bf16(pa0, bv0, O[dc], 0, 0, 0);
      short8 bv1 = *(const short8*)&Vs[(dc * 16 + r16) * 72 + 32 + kg * 8];
      O[dc] = __builtin_amdgcn_mfma_f32_16x16x32_bf16(pa1, bv1, O[dc], 0, 0, 0);
    }
  }

  // finalize: out[b, n=cc*64+qt*4+wv, e=(kg*4+r)*64 + dc*16 + r16]
  size_t obase = ((size_t)(b * 1024 + cc * 64 + qt * 4 + wv)) * 1024;
#pragma unroll
  for (int r = 0; r < 4; r++) {
    float inv = 1.0f / lo[r];
#pragma unroll
    for (int dc = 0; dc < 4; dc++)
      out[obase + (kg * 4 + r) * 64 + dc * 16 + r16] = O[dc][r] * inv;
  }
}

extern "C" void kernel_launch(void* const* d_in, const int* in_sizes, int n_in,
                              void* d_out, int out_size, void* d_ws, size_t ws_size,
                              hipStream_t stream) {
  const float* q  = (const float*)d_in[0];
  const float* k  = (const float*)d_in[1];
  const float* v  = (const float*)d_in[2];
  const float* wq = (const float*)d_in[3];
  const float* wk = (const float*)d_in[4];
  const float* wv = (const float*)d_in[5];
  ushort_t* ws = (ushort_t*)d_ws;   // needs ~56.7 MB
  float* out = (float*)d_out;

  cvt_kernel<<<7680, 256, 0, stream>>>(q, k, v, wq, wk, wv, ws);
  dim3 gg(32, 8, 3);
  gemm_qkv<<<gg, 256, 0, stream>>>(ws);
  dim3 ga(64, 16);
  attn_kernel<<<ga, 256, 0, stream>>>(ws, out);
}

// Round 11
// 192.317 us; speedup vs baseline: 1.2156x; 1.2156x over previous
//
#include <hip/hip_runtime.h>
#include <stdint.h>

typedef unsigned short ushort_t;
typedef __attribute__((ext_vector_type(8))) short short8;
typedef __attribute__((ext_vector_type(4))) float f32x4;
typedef __attribute__((ext_vector_type(4))) int int4v;

// ws layout (bf16 elements) -- total 28,311,552 el = 56.6 MB
#define OFF_VT   0u          // V transposed [(g*64+d)*1024 + m]  (overwrites dead QIN after gemm)
#define OFF_QIN  0u
#define OFF_KIN  4194304u
#define OFF_VIN  8388608u
#define OFF_WQ   12582912u
#define OFF_WK   13631488u
#define OFF_WV   14680064u
#define OFF_QP   15728640u   // Q projected (scaled by 0.125*log2e), [4096][1024]
#define OFF_KP   19922944u   // K projected, [4096][1024]
#define OFF_VP   24117248u   // V projected, normal layout [4096][1024]

__device__ __forceinline__ ushort_t f2bf(float f) {
  union { float f; unsigned u; } x; x.f = f;
  unsigned r = (x.u + 0x7fffu + ((x.u >> 16) & 1u)) >> 16;
  return (ushort_t)r;
}

__device__ __forceinline__ void gl_lds16(const void* g, void* l) {
  __builtin_amdgcn_global_load_lds(
      (const __attribute__((address_space(1))) void*)g,
      (__attribute__((address_space(3))) void*)l, 16, 0, 0);
}

// ---------------- convert fp32 -> bf16 (all six inputs) ----------------
__global__ void cvt_kernel(const float* __restrict__ q, const float* __restrict__ k,
                           const float* __restrict__ v, const float* __restrict__ wq,
                           const float* __restrict__ wk, const float* __restrict__ wv,
                           ushort_t* __restrict__ ws) {
  int cid = blockIdx.x * 256 + threadIdx.x;  // 1,966,080 chunks of 8 elems
  const float* src; int loc; unsigned dstoff;
  if (cid < 1572864) {            // q,k,v inputs
    int seg = cid >> 19; loc = cid & 524287;
    src = (seg == 0) ? q : (seg == 1) ? k : v;
    dstoff = (seg == 0) ? OFF_QIN : (seg == 1) ? OFF_KIN : OFF_VIN;
  } else {                        // weights
    int c2 = cid - 1572864; int seg = c2 >> 17; loc = c2 & 131071;
    src = (seg == 0) ? wq : (seg == 1) ? wk : wv;
    dstoff = (seg == 0) ? OFF_WQ : (seg == 1) ? OFF_WK : OFF_WV;
  }
  const float4* s4 = (const float4*)(src + (size_t)loc * 8);
  float4 a = s4[0], b = s4[1];
  short8 r;
  r[0] = f2bf(a.x); r[1] = f2bf(a.y); r[2] = f2bf(a.z); r[3] = f2bf(a.w);
  r[4] = f2bf(b.x); r[5] = f2bf(b.y); r[6] = f2bf(b.z); r[7] = f2bf(b.w);
  *(short8*)(ws + dstoff + (size_t)loc * 8) = r;
}

// ---------------- fused Q/K/V projection GEMM: C = A * W^T ----------------
__global__ __launch_bounds__(256) void gemm_qkv(ushort_t* __restrict__ ws) {
  int z = blockIdx.z;
  const ushort_t* A = ws + (z == 0 ? OFF_QIN : z == 1 ? OFF_KIN : OFF_VIN);
  const ushort_t* W = ws + (z == 0 ? OFF_WQ  : z == 1 ? OFF_WK  : OFF_WV);
  ushort_t* C       = ws + (z == 0 ? OFF_QP  : z == 1 ? OFF_KP  : OFF_VP);
  float scale = (z == 0) ? 0.18033688011112042f : 1.0f;  // (1/8)*log2(e)

  __shared__ ushort_t As[128 * 32];
  __shared__ ushort_t Bs[128 * 32];

  int tid = threadIdx.x, lane = tid & 63, wvid = tid >> 6;
  int wr = wvid >> 1, wc = wvid & 1;
  int r16 = lane & 15, kg = lane >> 4;
  int srow = lane >> 2;
  int scol = (lane & 3) * 8;

  int rowA0 = blockIdx.x * 128;
  int colB0 = blockIdx.y * 128;

  f32x4 acc[4][4];
#pragma unroll
  for (int m = 0; m < 4; m++)
#pragma unroll
    for (int n = 0; n < 4; n++) acc[m][n] = (f32x4){0.f, 0.f, 0.f, 0.f};

  for (int k0 = 0; k0 < 1024; k0 += 32) {
    __syncthreads();
#pragma unroll
    for (int r = 0; r < 2; r++) {
      int ch = wvid * 2 + r;
      int row = ch * 16 + srow;
      gl_lds16(A + (size_t)(rowA0 + row) * 1024 + k0 + scol, &As[ch * 512]);
      gl_lds16(W + (size_t)(colB0 + row) * 1024 + k0 + scol, &Bs[ch * 512]);
    }
    __syncthreads();
    short8 af[4], bfr[4];
#pragma unroll
    for (int m = 0; m < 4; m++)
      af[m] = *(const short8*)&As[(wr * 64 + m * 16 + r16) * 32 + kg * 8];
#pragma unroll
    for (int n = 0; n < 4; n++)
      bfr[n] = *(const short8*)&Bs[(wc * 64 + n * 16 + r16) * 32 + kg * 8];
#pragma unroll
    for (int m = 0; m < 4; m++)
#pragma unroll
      for (int n = 0; n < 4; n++)
        acc[m][n] = __builtin_amdgcn_mfma_f32_16x16x32_bf16(af[m], bfr[n], acc[m][n], 0, 0, 0);
  }

#pragma unroll
  for (int m = 0; m < 4; m++)
#pragma unroll
    for (int n = 0; n < 4; n++) {
      int col = colB0 + wc * 64 + n * 16 + r16;
#pragma unroll
      for (int r = 0; r < 4; r++) {
        int row = rowA0 + wr * 64 + m * 16 + kg * 4 + r;
        C[(size_t)row * 1024 + col] = f2bf(acc[m][n][r] * scale);
      }
    }
}

// ---------------- V transpose: VP [4096][1024] -> VT [(g*64+d)*1024 + m] ----------------
__global__ __launch_bounds__(256) void vtrans_kernel(ushort_t* __restrict__ ws) {
  int bid = blockIdx.x;                 // 256 blocks: 4b x 16c x 4tc
  int tc = bid & 3, c = (bid >> 2) & 15, b = bid >> 6;
  __shared__ ushort_t T[16 * 1024];
  const ushort_t* VP = ws + OFF_VP;
  ushort_t* VT = ws + OFF_VT;
  int tid = threadIdx.x;
  size_t gbase = ((size_t)(b * 1024 + c * 64 + tc * 16)) * 1024;
#pragma unroll
  for (int i = 0; i < 8; i++) {
    int L = (i * 256 + tid) * 8;
    *(short8*)&T[L] = *(const short8*)&VP[gbase + L];
  }
  __syncthreads();
  int d = tid & 63, sub = tid >> 6;     // lane=d: LDS reads land 2 lanes/bank (free)
  ushort_t tmp[64];
#pragma unroll
  for (int j = 0; j < 64; j++) {
    int t = sub * 4 + (j >> 4), h = j & 15;
    tmp[j] = T[t * 1024 + h * 64 + d];
  }
  size_t obase = ((size_t)((b * 16 + c) * 64 + d)) * 1024 + tc * 256 + sub * 64;
#pragma unroll
  for (int j = 0; j < 8; j++)
    *(short8*)&VT[obase + j * 8] = *(short8*)&tmp[j * 8];
}

// ---------------- flash attention, swapped-operand (S^T), KVBLK=128 ----------------
__global__ __launch_bounds__(256) void attn_kernel(const ushort_t* __restrict__ ws,
                                                   float* __restrict__ out) {
  const ushort_t* Qp = ws + OFF_QP;
  const ushort_t* Kp = ws + OFF_KP;
  const ushort_t* Vt = ws + OFF_VT;

  __shared__ ushort_t Ks[128 * 64];   // [k'][d], 16B-chunk XOR swizzle by (k'&7)
  __shared__ ushort_t Vs[64 * 128];   // [d][m'], 16B-chunk XOR swizzle by (d&7)

  int g = blockIdx.x;
  int qt = blockIdx.y;
  int b = g >> 4, cc = g & 15;
  int tid = threadIdx.x, lane = tid & 63, wvid = tid >> 6;
  int r16 = lane & 15, kg = lane >> 4;
  int xr = r16 & 7;
  const int nbase = b * 1024 + cc * 64;

  // Q fragments (B-operand): wave's q-rows m = qt*64 + wvid*16 + r16 -> n uniform, h=r16
  short8 aq[2];
  {
    size_t base = ((size_t)(nbase + qt * 4 + wvid)) * 1024 + r16 * 64;
    aq[0] = *(const short8*)&Qp[base + kg * 8];
    aq[1] = *(const short8*)&Qp[base + 32 + kg * 8];
  }

  // pre-swizzled staging offsets (per-lane), m173 pattern
  int koff[4], voff[4];
#pragma unroll
  for (int R = 0; R < 4; R++) {
    int L = (R * 256 + tid) * 8;
    koff[R] = (L & ~63) + ((((L >> 3) & 7) ^ ((L >> 6) & 7)) << 3);
    voff[R] = (L >> 7) * 1024 + ((((L >> 3) & 15) ^ ((L >> 7) & 7)) << 3);
  }
  size_t kbase = (size_t)(nbase)*1024;            // + it*8192 per iter
  size_t vbase = (size_t)g * 65536;               // + it*128 per iter

  f32x4 O[4];
#pragma unroll
  for (int i = 0; i < 4; i++) O[i] = (f32x4){0.f, 0.f, 0.f, 0.f};
  float mo = -1e30f, lo = 0.f;

  for (int it = 0; it < 8; it++) {
    __syncthreads();
    {
      size_t ktb = kbase + (size_t)it * 8192;
      size_t vtb = vbase + (size_t)it * 128;
#pragma unroll
      for (int R = 0; R < 4; R++) {
        gl_lds16(Kp + ktb + koff[R], &Ks[R * 2048 + wvid * 512]);
        gl_lds16(Vt + vtb + voff[R], &Vs[R * 2048 + wvid * 512]);
      }
    }
    __syncthreads();

    // S^T = K Q^T : lane holds S^T[k' = jc*16+kg*4+r][q=r16]
    f32x4 s[8];
#pragma unroll
    for (int jc = 0; jc < 8; jc++) {
      s[jc] = (f32x4){0.f, 0.f, 0.f, 0.f};
#pragma unroll
      for (int c2 = 0; c2 < 2; c2++) {
        short8 kf = *(const short8*)&Ks[(jc * 16 + r16) * 64 + (((c2 * 4 + kg) ^ xr) << 3)];
        s[jc] = __builtin_amdgcn_mfma_f32_16x16x32_bf16(kf, aq[c2], s[jc], 0, 0, 0);
      }
    }

    // per-lane softmax over 32 in-register scores + 2-shuffle cross-kg reduce
    float tm = s[0][0];
#pragma unroll
    for (int jc = 0; jc < 8; jc++)
#pragma unroll
      for (int r = 0; r < 4; r++) tm = fmaxf(tm, s[jc][r]);
    tm = fmaxf(tm, __shfl_xor(tm, 16));
    tm = fmaxf(tm, __shfl_xor(tm, 32));

    if (!__all(tm <= mo + 8.0f)) {      // defer-max (T13)
      float mn = fmaxf(mo, tm);
      float al = exp2f(mo - mn);
#pragma unroll
      for (int dc = 0; dc < 4; dc++) O[dc] = O[dc] * al;
      lo *= al;
      mo = mn;
    }

    float ls = 0.f;
#pragma unroll
    for (int jc = 0; jc < 8; jc++)
#pragma unroll
      for (int r = 0; r < 4; r++) {
        float pv = exp2f(s[jc][r] - mo);
        s[jc][r] = pv;
        ls += pv;
      }
    ls += __shfl_xor(ls, 16);
    ls += __shfl_xor(ls, 32);
    lo += ls;

    // pack P^T to bf16 pairs: cp[jc][u] covers k' = jc*16 + kg*4 + {2u,2u+1}
    int cp[8][2];
#pragma unroll
    for (int jc = 0; jc < 8; jc++) {
#pragma unroll
      for (int u = 0; u < 2; u++) {
        int pk;
        asm("v_cvt_pk_bf16_f32 %0, %1, %2" : "=v"(pk) : "v"(s[jc][2 * u]), "v"(s[jc][2 * u + 1]));
        cp[jc][u] = pk;
      }
    }

    // PV: O^T += V^T * P^T.  B-frag at lane kg needs k' = kc*32 + kg*8 + {0..7}.
    // Pure shfl_xor redistribution (verified mapping):
    //  pair pp = kc*16+kg*4+t lives at lane kg'=(kg&1)*2+(t>>1) in cp[2kc+(kg>>1)][t&1].
#pragma unroll
    for (int kc = 0; kc < 4; kc++) {
      int a0 = cp[2 * kc][0], a1 = cp[2 * kc][1];
      int b0 = cp[2 * kc + 1][0], b1 = cp[2 * kc + 1][1];
      int a0x = __shfl_xor(a0, 16), a1x = __shfl_xor(a1, 16);
      int b0x = __shfl_xor(b0, 16), b1x = __shfl_xor(b1, 16);
      bool lodd = (kg & 1);
      int Aq0 = lodd ? a0x : a0, Aq1 = lodd ? a1x : a1;
      int Aq2 = lodd ? a0 : a0x, Aq3 = lodd ? a1 : a1x;
      int Bq0 = lodd ? b0x : b0, Bq1 = lodd ? b1x : b1;
      int Bq2 = lodd ? b0 : b0x, Bq3 = lodd ? b1 : b1x;
      bool hi = (kg >> 1) & 1;
      int x0 = hi ? Aq0 : Bq0, x1 = hi ? Aq1 : Bq1;
      int x2 = hi ? Aq2 : Bq2, x3 = hi ? Aq3 : Bq3;
      int y0 = __shfl_xor(x0, 32), y1 = __shfl_xor(x1, 32);
      int y2 = __shfl_xor(x2, 32), y3 = __shfl_xor(x3, 32);
      int w0 = (kg == 0) ? Aq0 : (kg == 3) ? Bq0 : y0;
      int w1 = (kg == 0) ? Aq1 : (kg == 3) ? Bq1 : y1;
      int w2 = (kg == 0) ? Aq2 : (kg == 3) ? Bq2 : y2;
      int w3 = (kg == 0) ? Aq3 : (kg == 3) ? Bq3 : y3;
      int4v w; w[0] = w0; w[1] = w1; w[2] = w2; w[3] = w3;
      short8 pf = *(short8*)&w;
#pragma unroll
      for (int dc = 0; dc < 4; dc++) {
        short8 vf = *(const short8*)&Vs[(dc * 16 + r16) * 128 + (((kc * 4 + kg) ^ xr) << 3)];
        O[dc] = __builtin_amdgcn_mfma_f32_16x16x32_bf16(vf, pf, O[dc], 0, 0, 0);
      }
    }
  }

  // epilogue: O^T[d][q]: d = dc*16+kg*4+r, q=r16; e = r16*64 + d, n uniform
  float inv = 1.0f / lo;
  size_t obase = ((size_t)(nbase + qt * 4 + wvid)) * 1024 + r16 * 64;
#pragma unroll
  for (int dc = 0; dc < 4; dc++) {
    float4 o4;
    o4.x = O[dc][0] * inv; o4.y = O[dc][1] * inv;
    o4.z = O[dc][2] * inv; o4.w = O[dc][3] * inv;
    *(float4*)&out[obase + dc * 16 + kg * 4] = o4;
  }
}

extern "C" void kernel_launch(void* const* d_in, const int* in_sizes, int n_in,
                              void* d_out, int out_size, void* d_ws, size_t ws_size,
                              hipStream_t stream) {
  const float* q  = (const float*)d_in[0];
  const float* k  = (const float*)d_in[1];
  const float* v  = (const float*)d_in[2];
  const float* wq = (const float*)d_in[3];
  const float* wk = (const float*)d_in[4];
  const float* wv = (const float*)d_in[5];
  ushort_t* ws = (ushort_t*)d_ws;   // ~56.6 MB
  float* out = (float*)d_out;

  cvt_kernel<<<7680, 256, 0, stream>>>(q, k, v, wq, wk, wv, ws);
  dim3 gg(32, 8, 3);
  gemm_qkv<<<gg, 256, 0, stream>>>(ws);
  vtrans_kernel<<<256, 256, 0, stream>>>(ws);
  dim3 ga(64, 16);
  attn_kernel<<<ga, 256, 0, stream>>>(ws, out);
}

// Round 13
// 190.203 us; speedup vs baseline: 1.2291x; 1.0111x over previous
//
#include <hip/hip_runtime.h>
#include <stdint.h>

typedef unsigned short ushort_t;
typedef __attribute__((ext_vector_type(8))) short short8;
typedef __attribute__((ext_vector_type(4))) float f32x4;

// ws layout (bf16 elements) -- total 28,311,552 el = 56.6 MB
#define OFF_VT   0u          // V transposed [(g*64+d)*1024 + m]  (overwrites dead QIN after gemm)
#define OFF_QIN  0u
#define OFF_KIN  4194304u
#define OFF_VIN  8388608u
#define OFF_WQ   12582912u
#define OFF_WK   13631488u
#define OFF_WV   14680064u
#define OFF_QP   15728640u   // Q projected (scaled by 0.125*log2e), [4096][1024]
#define OFF_KP   19922944u   // K projected, [4096][1024]
#define OFF_VP   24117248u   // V projected, normal layout [4096][1024]

__device__ __forceinline__ ushort_t f2bf(float f) {
  union { float f; unsigned u; } x; x.f = f;
  unsigned r = (x.u + 0x7fffu + ((x.u >> 16) & 1u)) >> 16;
  return (ushort_t)r;
}

__device__ __forceinline__ void gl_lds16(const void* g, void* l) {
  __builtin_amdgcn_global_load_lds(
      (const __attribute__((address_space(1))) void*)g,
      (__attribute__((address_space(3))) void*)l, 16, 0, 0);
}

// ---------------- convert fp32 -> bf16 (all six inputs) ----------------
__global__ void cvt_kernel(const float* __restrict__ q, const float* __restrict__ k,
                           const float* __restrict__ v, const float* __restrict__ wq,
                           const float* __restrict__ wk, const float* __restrict__ wv,
                           ushort_t* __restrict__ ws) {
  int cid = blockIdx.x * 256 + threadIdx.x;  // 1,966,080 chunks of 8 elems
  const float* src; int loc; unsigned dstoff;
  if (cid < 1572864) {            // q,k,v inputs
    int seg = cid >> 19; loc = cid & 524287;
    src = (seg == 0) ? q : (seg == 1) ? k : v;
    dstoff = (seg == 0) ? OFF_QIN : (seg == 1) ? OFF_KIN : OFF_VIN;
  } else {                        // weights
    int c2 = cid - 1572864; int seg = c2 >> 17; loc = c2 & 131071;
    src = (seg == 0) ? wq : (seg == 1) ? wk : wv;
    dstoff = (seg == 0) ? OFF_WQ : (seg == 1) ? OFF_WK : OFF_WV;
  }
  const float4* s4 = (const float4*)(src + (size_t)loc * 8);
  float4 a = s4[0], b = s4[1];
  short8 r;
  r[0] = f2bf(a.x); r[1] = f2bf(a.y); r[2] = f2bf(a.z); r[3] = f2bf(a.w);
  r[4] = f2bf(b.x); r[5] = f2bf(b.y); r[6] = f2bf(b.z); r[7] = f2bf(b.w);
  *(short8*)(ws + dstoff + (size_t)loc * 8) = r;
}

// ---------------- fused Q/K/V projection GEMM: C = A * W^T ----------------
__global__ __launch_bounds__(256) void gemm_qkv(ushort_t* __restrict__ ws) {
  int z = blockIdx.z;
  const ushort_t* A = ws + (z == 0 ? OFF_QIN : z == 1 ? OFF_KIN : OFF_VIN);
  const ushort_t* W = ws + (z == 0 ? OFF_WQ  : z == 1 ? OFF_WK  : OFF_WV);
  ushort_t* C       = ws + (z == 0 ? OFF_QP  : z == 1 ? OFF_KP  : OFF_VP);
  float scale = (z == 0) ? 0.18033688011112042f : 1.0f;  // (1/8)*log2(e)

  __shared__ ushort_t As[128 * 32];
  __shared__ ushort_t Bs[128 * 32];

  int tid = threadIdx.x, lane = tid & 63, wvid = tid >> 6;
  int wr = wvid >> 1, wc = wvid & 1;
  int r16 = lane & 15, kg = lane >> 4;
  int srow = lane >> 2;
  int scol = (lane & 3) * 8;

  int rowA0 = blockIdx.x * 128;
  int colB0 = blockIdx.y * 128;

  f32x4 acc[4][4];
#pragma unroll
  for (int m = 0; m < 4; m++)
#pragma unroll
    for (int n = 0; n < 4; n++) acc[m][n] = (f32x4){0.f, 0.f, 0.f, 0.f};

  for (int k0 = 0; k0 < 1024; k0 += 32) {
    __syncthreads();
#pragma unroll
    for (int r = 0; r < 2; r++) {
      int ch = wvid * 2 + r;
      int row = ch * 16 + srow;
      gl_lds16(A + (size_t)(rowA0 + row) * 1024 + k0 + scol, &As[ch * 512]);
      gl_lds16(W + (size_t)(colB0 + row) * 1024 + k0 + scol, &Bs[ch * 512]);
    }
    __syncthreads();
    short8 af[4], bfr[4];
#pragma unroll
    for (int m = 0; m < 4; m++)
      af[m] = *(const short8*)&As[(wr * 64 + m * 16 + r16) * 32 + kg * 8];
#pragma unroll
    for (int n = 0; n < 4; n++)
      bfr[n] = *(const short8*)&Bs[(wc * 64 + n * 16 + r16) * 32 + kg * 8];
#pragma unroll
    for (int m = 0; m < 4; m++)
#pragma unroll
      for (int n = 0; n < 4; n++)
        acc[m][n] = __builtin_amdgcn_mfma_f32_16x16x32_bf16(af[m], bfr[n], acc[m][n], 0, 0, 0);
  }

#pragma unroll
  for (int m = 0; m < 4; m++)
#pragma unroll
    for (int n = 0; n < 4; n++) {
      int col = colB0 + wc * 64 + n * 16 + r16;
#pragma unroll
      for (int r = 0; r < 4; r++) {
        int row = rowA0 + wr * 64 + m * 16 + kg * 4 + r;
        C[(size_t)row * 1024 + col] = f2bf(acc[m][n][r] * scale);
      }
    }
}

// ---------------- V transpose: VP [4096][1024] -> VT [(g*64+d)*1024 + m] ----------------
__global__ __launch_bounds__(256) void vtrans_kernel(ushort_t* __restrict__ ws) {
  int bid = blockIdx.x;                 // 256 blocks: 4b x 16c x 4tc
  int tc = bid & 3, c = (bid >> 2) & 15, b = bid >> 6;
  __shared__ ushort_t T[16 * 1024];
  const ushort_t* VP = ws + OFF_VP;
  ushort_t* VT = ws + OFF_VT;
  int tid = threadIdx.x;
  size_t gbase = ((size_t)(b * 1024 + c * 64 + tc * 16)) * 1024;
#pragma unroll
  for (int i = 0; i < 8; i++) {
    int L = (i * 256 + tid) * 8;
    *(short8*)&T[L] = *(const short8*)&VP[gbase + L];
  }
  __syncthreads();
  int d = tid & 63, sub = tid >> 6;     // lane=d: LDS reads land 2 lanes/bank (free)
  ushort_t tmp[64];
#pragma unroll
  for (int j = 0; j < 64; j++) {
    int t = sub * 4 + (j >> 4), h = j & 15;
    tmp[j] = T[t * 1024 + h * 64 + d];
  }
  size_t obase = ((size_t)((b * 16 + c) * 64 + d)) * 1024 + tc * 256 + sub * 64;
#pragma unroll
  for (int j = 0; j < 8; j++)
    *(short8*)&VT[obase + j * 8] = *(short8*)&tmp[j * 8];
}

// ---------------- flash attention, swapped-operand (S^T), KVBLK=128 ----------------
// P path: wave-private LDS slice carved from Ks (dead after QK^T; mid-barrier guards reuse)
__global__ __launch_bounds__(256) void attn_kernel(const ushort_t* __restrict__ ws,
                                                   float* __restrict__ out) {
  const ushort_t* Qp = ws + OFF_QP;
  const ushort_t* Kp = ws + OFF_KP;
  const ushort_t* Vt = ws + OFF_VT;

  __shared__ ushort_t Ks[128 * 64];   // [k'][d], 16B-chunk XOR swizzle by (k'&7); P-buffer after QK^T
  __shared__ ushort_t Vs[64 * 128];   // [d][m'], 16B-chunk XOR swizzle by (d&7)

  int g = blockIdx.x;
  int qt = blockIdx.y;
  int b = g >> 4, cc = g & 15;
  int tid = threadIdx.x, lane = tid & 63, wvid = tid >> 6;
  int r16 = lane & 15, kg = lane >> 4;
  int xr = r16 & 7;
  const int nbase = b * 1024 + cc * 64;

  // Q fragments (B-operand): wave's q-rows m = qt*64 + wvid*16 + r16 -> n uniform, h=r16
  short8 aq[2];
  {
    size_t base = ((size_t)(nbase + qt * 4 + wvid)) * 1024 + r16 * 64;
    aq[0] = *(const short8*)&Qp[base + kg * 8];
    aq[1] = *(const short8*)&Qp[base + 32 + kg * 8];
  }

  // pre-swizzled staging offsets (per-lane), m173 pattern
  int koff[4], voff[4];
#pragma unroll
  for (int R = 0; R < 4; R++) {
    int L = (R * 256 + tid) * 8;
    koff[R] = (L & ~63) + ((((L >> 3) & 7) ^ ((L >> 6) & 7)) << 3);
    voff[R] = (L >> 7) * 1024 + ((((L >> 3) & 15) ^ ((L >> 7) & 7)) << 3);
  }
  size_t kbase = (size_t)(nbase)*1024;            // + it*8192 per iter
  size_t vbase = (size_t)g * 65536;               // + it*128 per iter

  f32x4 O[4];
#pragma unroll
  for (int i = 0; i < 4; i++) O[i] = (f32x4){0.f, 0.f, 0.f, 0.f};
  float mo = -1e30f, lo = 0.f;

  for (int it = 0; it < 8; it++) {
    __syncthreads();
    {
      size_t ktb = kbase + (size_t)it * 8192;
      size_t vtb = vbase + (size_t)it * 128;
#pragma unroll
      for (int R = 0; R < 4; R++) {
        gl_lds16(Kp + ktb + koff[R], &Ks[R * 2048 + wvid * 512]);
        gl_lds16(Vt + vtb + voff[R], &Vs[R * 2048 + wvid * 512]);
      }
    }
    __syncthreads();

    // S^T = K Q^T : lane holds S^T[k' = jc*16+kg*4+r][q=r16]
    f32x4 s[8];
#pragma unroll
    for (int jc = 0; jc < 8; jc++) {
      s[jc] = (f32x4){0.f, 0.f, 0.f, 0.f};
#pragma unroll
      for (int c2 = 0; c2 < 2; c2++) {
        short8 kf = *(const short8*)&Ks[(jc * 16 + r16) * 64 + (((c2 * 4 + kg) ^ xr) << 3)];
        s[jc] = __builtin_amdgcn_mfma_f32_16x16x32_bf16(kf, aq[c2], s[jc], 0, 0, 0);
      }
    }

    // per-lane softmax over 32 in-register scores + 2-shuffle cross-kg reduce
    float tm = s[0][0];
#pragma unroll
    for (int jc = 0; jc < 8; jc++)
#pragma unroll
      for (int r = 0; r < 4; r++) tm = fmaxf(tm, s[jc][r]);
    tm = fmaxf(tm, __shfl_xor(tm, 16));
    tm = fmaxf(tm, __shfl_xor(tm, 32));

    if (!__all(tm <= mo + 8.0f)) {      // defer-max (T13)
      float mn = fmaxf(mo, tm);
      float al = exp2f(mo - mn);
#pragma unroll
      for (int dc = 0; dc < 4; dc++) O[dc] = O[dc] * al;
      lo *= al;
      mo = mn;
    }

    float ls = 0.f;
#pragma unroll
    for (int jc = 0; jc < 8; jc++)
#pragma unroll
      for (int r = 0; r < 4; r++) {
        float pv = exp2f(s[jc][r] - mo);
        s[jc][r] = pv;
        ls += pv;
      }
    ls += __shfl_xor(ls, 16);
    ls += __shfl_xor(ls, 32);
    lo += ls;

    // all waves done reading Ks for QK^T -> safe to reuse Ks as P-buffer
    __syncthreads();

    // P^T write: wave-private slice Pw = Ks[wvid*2048 ..], layout [q=16][k'=128],
    // 16B-chunk XOR swizzle by (q&7).  Pair (k'=jc*16+kg*4+2u, q=r16):
    //   chunk = k'>>3 = jc*2+(kg>>1), pos = (k'&7)>>1 = (kg&1)*2+u
    ushort_t* Pw = &Ks[wvid * 2048];
#pragma unroll
    for (int jc = 0; jc < 8; jc++) {
#pragma unroll
      for (int u = 0; u < 2; u++) {
        int pk;
        asm("v_cvt_pk_bf16_f32 %0, %1, %2" : "=v"(pk) : "v"(s[jc][2 * u]), "v"(s[jc][2 * u + 1]));
        int chunk = jc * 2 + (kg >> 1);
        int idx = r16 * 128 + ((chunk ^ xr) << 3) + ((kg & 1) * 2 + u) * 2;
        *(int*)&Pw[idx] = pk;
      }
    }

    // PV: O^T += V^T * P^T.  B-frag at lane (r16,kg): row q=r16, k' = kc*32+kg*8..+8
#pragma unroll
    for (int kc = 0; kc < 4; kc++) {
      short8 pf = *(const short8*)&Pw[r16 * 128 + (((kc * 4 + kg) ^ xr) << 3)];
#pragma unroll
      for (int dc = 0; dc < 4; dc++) {
        short8 vf = *(const short8*)&Vs[(dc * 16 + r16) * 128 + (((kc * 4 + kg) ^ xr) << 3)];
        O[dc] = __builtin_amdgcn_mfma_f32_16x16x32_bf16(vf, pf, O[dc], 0, 0, 0);
      }
    }
  }

  // epilogue: O^T[d][q]: d = dc*16+kg*4+r, q=r16; e = r16*64 + d, n uniform
  float inv = 1.0f / lo;
  size_t obase = ((size_t)(nbase + qt * 4 + wvid)) * 1024 + r16 * 64;
#pragma unroll
  for (int dc = 0; dc < 4; dc++) {
    float4 o4;
    o4.x = O[dc][0] * inv; o4.y = O[dc][1] * inv;
    o4.z = O[dc][2] * inv; o4.w = O[dc][3] * inv;
    *(float4*)&out[obase + dc * 16 + kg * 4] = o4;
  }
}

extern "C" void kernel_launch(void* const* d_in, const int* in_sizes, int n_in,
                              void* d_out, int out_size, void* d_ws, size_t ws_size,
                              hipStream_t stream) {
  const float* q  = (const float*)d_in[0];
  const float* k  = (const float*)d_in[1];
  const float* v  = (const float*)d_in[2];
  const float* wq = (const float*)d_in[3];
  const float* wk = (const float*)d_in[4];
  const float* wv = (const float*)d_in[5];
  ushort_t* ws = (ushort_t*)d_ws;   // ~56.6 MB
  float* out = (float*)d_out;

  cvt_kernel<<<7680, 256, 0, stream>>>(q, k, v, wq, wk, wv, ws);
  dim3 gg(32, 8, 3);
  gemm_qkv<<<gg, 256, 0, stream>>>(ws);
  vtrans_kernel<<<256, 256, 0, stream>>>(ws);
  dim3 ga(64, 16);
  attn_kernel<<<ga, 256, 0, stream>>>(ws, out);
}